// Round 8
// baseline (127.092 us; speedup 1.0000x reference)
//
#include <hip/hip_runtime.h>

#define M_VOX   100000
#define N_VOX   200000
#define K_VOL   27
#define C_IN    32
#define C_OUT   64

#define STG0        14                 // offsets in LDS stage 0
#define STG1        (K_VOL - STG0)     // 13 offsets in stage 1
#define BLK_THREADS 512                // 8 waves; 256 voxels per block
#define VOX_PER_BLK 256                // 32 voxels per wave (32x32 MFMA)
#define BURST       5                  // gather batch (offsets): loads precede uses

typedef __bf16 bf16x8 __attribute__((ext_vector_type(8)));
typedef float  floatx4  __attribute__((ext_vector_type(4)));
typedef float  floatx16 __attribute__((ext_vector_type(16)));

// ---- d_ws layout ----
// featsB : (N_VOX+1) rows x 32 bf16 (64 B/row), row N_VOX all-zero
// Bfrag  : 27 * 256 * 16 B bf16 weights in 32x32x16 MFMA fragment order
#define FEATSB_BYTES  ((N_VOX + 1) * C_IN * 2)
#define BFRAG_OFF     FEATSB_BYTES

// ---------- fused prep: feats fp32->bf16 (+zero row) | weights->frag ----------
#define FEAT_CHUNKS   ((N_VOX + 1) * 4)
#define FEAT_BLOCKS   ((FEAT_CHUNKS + 255) / 256)
__global__ __launch_bounds__(256) void prep_all(
    const float* __restrict__ feats, const float* __restrict__ kernelw,
    __bf16* __restrict__ featsB, bf16x8* __restrict__ Bfrag)
{
    if (blockIdx.x < FEAT_BLOCKS) {
        const int c = blockIdx.x * 256 + threadIdx.x;
        if (c >= FEAT_CHUNKS) return;
        bf16x8 v;
        if (c < N_VOX * 4) {
            floatx4 f0 = *(const floatx4*)(feats + c * 8);
            floatx4 f1 = *(const floatx4*)(feats + c * 8 + 4);
#pragma unroll
            for (int j = 0; j < 4; ++j) { v[j] = (__bf16)f0[j]; v[4 + j] = (__bf16)f1[j]; }
        } else {
#pragma unroll
            for (int j = 0; j < 8; ++j) v[j] = (__bf16)0.0f;
        }
        *(bf16x8*)(featsB + c * 8) = v;
    } else {
        // 32x32x16 B-frag: frag = h*2 + t (h = K-half, t = col-tile of 32)
        // slot element j = kernel[k][h*16 + (lane>>5)*8 + j][t*32 + (lane&31)]
        const int k    = blockIdx.x - FEAT_BLOCKS;
        const int tid  = threadIdx.x;
        const int frag = tid >> 6;
        const int lane = tid & 63;
        const int h    = frag >> 1;
        const int t    = frag & 1;
        const int c32  = lane & 31;
        const int half = lane >> 5;
        const float* kp = kernelw + k * C_IN * C_OUT
                        + (h * 16 + half * 8) * C_OUT + t * 32 + c32;
        bf16x8 b;
#pragma unroll
        for (int j = 0; j < 8; ++j) b[j] = (__bf16)kp[j * C_OUT];
        Bfrag[k * 256 + tid] = b;
    }
}

// ---------- main ----------
// 32x32x16 MFMA: wave = 32 voxels x 64 out-channels (2 col-tiles, 2 K-halves
// -> 4 MFMAs and 4 ds_read_b128 per wave-offset, HALF the per-voxel LDS-read
// pipe of the 16x16x32 version — the largest modeled on-CU pipe).
// Block = 512 thr = 8 waves = 256 voxels; B-frags staged in LDS (14+13).
// A-frag (32x32x16): A[m=lane&31][k=(lane>>5)*8+j]; per offset lane loads
// two bf16x8 from its row (K-halves at +0 and +16 elements).
// C/D: col=lane&31, row=(reg&3)+8*(reg>>2)+4*(lane>>5).
__global__ __launch_bounds__(BLK_THREADS) void sparse_conv_mfma(
    const __bf16* __restrict__ featsB,
    const bf16x8* __restrict__ BfragG,
    const int* __restrict__ in_idx,
    const int* __restrict__ mask,
    float* __restrict__ out)
{
    __shared__ bf16x8 ldsB[STG0 * 256];   // 57,344 B

    const int tid  = threadIdx.x;
    const int lane = tid & 63;
    const int wv   = tid >> 6;
    const int c32  = lane & 31;
    const int half = lane >> 5;

    const int m0 = blockIdx.x * VOX_PER_BLK + wv * 32;
    const bool active = (m0 < M_VOX);   // M_VOX%32==0: waves all-or-nothing

    // stage offsets 0..13 into LDS (all waves participate — barrier safety)
#pragma unroll
    for (int i = tid; i < STG0 * 256; i += BLK_THREADS) ldsB[i] = BfragG[i];

    // full index chain up front: mask fused -> zero row N_VOX
    int mi[K_VOL];
    if (active) {
#pragma unroll
        for (int k = 0; k < K_VOL; ++k) {
            const int ix = in_idx[k * M_VOX + m0 + c32];
            const int mk = mask[k * M_VOX + m0 + c32];
            mi[k] = mk ? ix : N_VOX;
        }
    }
    __syncthreads();   // LDS stage 0 ready

    floatx16 accT0 = {0.f}, accT1 = {0.f};
#pragma unroll
    for (int i = 0; i < 16; ++i) { accT0[i] = 0.f; accT1[i] = 0.f; }

    const bf16x8* lbase = ldsB + lane;
    const __bf16* fbase = featsB + half * 8;   // + mi*32 (+16 for K-half 1)

    bf16x8 A0[BURST], A1[BURST];

    // batch = up to BURST offsets: all gathers issued before any MFMA use
#define GATHER_BATCH(KB, NB, LOFF)                                            \
    {                                                                          \
        _Pragma("unroll")                                                      \
        for (int j = 0; j < (NB); ++j) {                                       \
            const __bf16* rp = fbase + (size_t)mi[(KB) + j] * C_IN;            \
            A0[j] = *(const bf16x8*)(rp);                                      \
            A1[j] = *(const bf16x8*)(rp + 16);                                 \
        }                                                                      \
        _Pragma("unroll")                                                      \
        for (int j = 0; j < (NB); ++j) {                                       \
            const int kl = (LOFF) + j;                                         \
            bf16x8 b00 = lbase[(kl * 4 + 0) * 64];  /* h0,t0 */                \
            bf16x8 b01 = lbase[(kl * 4 + 1) * 64];  /* h0,t1 */                \
            bf16x8 b10 = lbase[(kl * 4 + 2) * 64];  /* h1,t0 */                \
            bf16x8 b11 = lbase[(kl * 4 + 3) * 64];  /* h1,t1 */                \
            accT0 = __builtin_amdgcn_mfma_f32_32x32x16_bf16(A0[j], b00, accT0, 0, 0, 0); \
            accT1 = __builtin_amdgcn_mfma_f32_32x32x16_bf16(A0[j], b01, accT1, 0, 0, 0); \
            accT0 = __builtin_amdgcn_mfma_f32_32x32x16_bf16(A1[j], b10, accT0, 0, 0, 0); \
            accT1 = __builtin_amdgcn_mfma_f32_32x32x16_bf16(A1[j], b11, accT1, 0, 0, 0); \
        }                                                                      \
    }

    if (active) {
        GATHER_BATCH(0, BURST, 0)                    // offsets 0..4
        GATHER_BATCH(BURST, BURST, BURST)            // offsets 5..9
        GATHER_BATCH(2 * BURST, STG0 - 2 * BURST, 2 * BURST)   // offsets 10..13
    }

    // ---- restage LDS with offsets 14..26 ----
    __syncthreads();   // everyone done reading LDS stage 0
#pragma unroll
    for (int i = tid; i < STG1 * 256; i += BLK_THREADS)
        ldsB[i] = BfragG[STG0 * 256 + i];
    __syncthreads();   // LDS stage 1 ready

    if (active) {
        GATHER_BATCH(STG0, BURST, 0)                             // 14..18
        GATHER_BATCH(STG0 + BURST, BURST, BURST)                 // 19..23
        GATHER_BATCH(STG0 + 2 * BURST, STG1 - 2 * BURST, 2 * BURST) // 24..26

        // C/D: col=lane&31, row=(reg&3)+8*(reg>>2)+4*half
        float* ob = out + (size_t)m0 * C_OUT + c32;
#pragma unroll
        for (int r = 0; r < 16; ++r) {
            const int row = (r & 3) + 8 * (r >> 2) + 4 * half;
            ob[(size_t)row * C_OUT + 0]  = accT0[r];
            ob[(size_t)row * C_OUT + 32] = accT1[r];
        }
    }
#undef GATHER_BATCH
}

extern "C" void kernel_launch(void* const* d_in, const int* in_sizes, int n_in,
                              void* d_out, int out_size, void* d_ws, size_t ws_size,
                              hipStream_t stream) {
    const float* feats   = (const float*)d_in[0];
    const float* kernelw = (const float*)d_in[1];
    const int*   in_idx  = (const int*)d_in[2];
    const int*   maskp   = (const int*)d_in[3];
    float*       out     = (float*)d_out;

    __bf16* featsB = (__bf16*)d_ws;
    bf16x8* BfragP = (bf16x8*)((char*)d_ws + BFRAG_OFF);

    prep_all<<<dim3(FEAT_BLOCKS + K_VOL), dim3(256), 0, stream>>>(
        feats, kernelw, featsB, BfragP);

    const int blocks = (M_VOX + VOX_PER_BLK - 1) / VOX_PER_BLK;   // 391
    sparse_conv_mfma<<<dim3(blocks), dim3(BLK_THREADS), 0, stream>>>(
        featsB, BfragP, in_idx, maskp, out);
}

// Round 9
// 120.492 us; speedup vs baseline: 1.0548x; 1.0548x over previous
//
#include <hip/hip_runtime.h>

#define M_VOX   100000
#define N_VOX   200000
#define K_VOL   27
#define C_IN    32
#define C_OUT   64

#define STG0        14                 // offsets in LDS stage 0
#define STG1        (K_VOL - STG0)     // 13 offsets in stage 1
#define BLK_THREADS 512                // 8 waves; 128 voxels per block
#define VOX_PER_BLK 128
#define BURST       7                  // gather batch: loads issued before uses

typedef __bf16 bf16x8 __attribute__((ext_vector_type(8)));
typedef float  floatx4 __attribute__((ext_vector_type(4)));

// ---- d_ws layout ----
// featsB : (N_VOX+1) rows x 32 bf16 (64 B/row), row N_VOX all-zero
// Bfrag  : 27 * 256 * 16 B bf16 weights in MFMA fragment order
#define FEATSB_BYTES  ((N_VOX + 1) * C_IN * 2)
#define BFRAG_OFF     FEATSB_BYTES

// ---------- fused prep: feats fp32->bf16 (+zero row) | weights->frag ----------
#define FEAT_CHUNKS   ((N_VOX + 1) * 4)
#define FEAT_BLOCKS   ((FEAT_CHUNKS + 255) / 256)
__global__ __launch_bounds__(256) void prep_all(
    const float* __restrict__ feats, const float* __restrict__ kernelw,
    __bf16* __restrict__ featsB, bf16x8* __restrict__ Bfrag)
{
    if (blockIdx.x < FEAT_BLOCKS) {
        const int c = blockIdx.x * 256 + threadIdx.x;
        if (c >= FEAT_CHUNKS) return;
        bf16x8 v;
        if (c < N_VOX * 4) {
            floatx4 f0 = *(const floatx4*)(feats + c * 8);
            floatx4 f1 = *(const floatx4*)(feats + c * 8 + 4);
#pragma unroll
            for (int j = 0; j < 4; ++j) { v[j] = (__bf16)f0[j]; v[4 + j] = (__bf16)f1[j]; }
        } else {
#pragma unroll
            for (int j = 0; j < 8; ++j) v[j] = (__bf16)0.0f;
        }
        *(bf16x8*)(featsB + c * 8) = v;
    } else {
        // weight frag: block k, thread tid -> slot (tile=tid>>6, lane=tid&63)
        // element j = kernel[k][((lane>>4)&3)*8 + j][tile*16 + (lane&15)]
        const int k    = blockIdx.x - FEAT_BLOCKS;
        const int tid  = threadIdx.x;
        const int tile = tid >> 6;
        const int col  = tid & 15;
        const int quad = (tid >> 4) & 3;
        const float* kp = kernelw + k * C_IN * C_OUT + quad * 8 * C_OUT + tile * 16 + col;
        bf16x8 b;
#pragma unroll
        for (int j = 0; j < 8; ++j) b[j] = (__bf16)kp[j * C_OUT];
        Bfrag[k * 256 + tid] = b;
    }
}

// ---------- main ----------
// Best-known configuration (r7). Wave = 16 voxels x 64 out-channels;
// block = 512 thr = 8 waves; B-frags staged in LDS (14+13 offsets, 57,344 B)
// so the weight table is read from global once per block. Gathers issued in
// bursts of 7 (loads precede uses -> MLP 7/wave). 2 blocks/CU residency.
// Measured bound (r5-r8 experiments): scattered 64-B gather service in
// L2/L3 (~86 MB random requests vs 12.8 MB table) — insensitive to MFMA
// shape, gather MLP, occupancy, and LDS-pipe load. This is the floor.
// A-frag (16x16x32 bf16): A[m=lane&15][k=(lane>>4)*8+j]
// C/D: col=lane&15 (channel in tile), row=(lane>>4)*4+reg (voxel).
__global__ __launch_bounds__(BLK_THREADS) void sparse_conv_mfma(
    const __bf16* __restrict__ featsB,
    const bf16x8* __restrict__ BfragG,
    const int* __restrict__ in_idx,
    const int* __restrict__ mask,
    float* __restrict__ out)
{
    __shared__ bf16x8 ldsB[STG0 * 256];   // 57,344 B

    const int tid  = threadIdx.x;
    const int lane = tid & 63;
    const int wv   = tid >> 6;
    const int col  = lane & 15;
    const int quad = lane >> 4;

    const int m0 = blockIdx.x * VOX_PER_BLK + wv * 16;
    const bool active = (m0 < M_VOX);   // M_VOX%16==0: waves all-or-nothing

    // stage offsets 0..13 into LDS (all waves participate — barrier safety)
#pragma unroll
    for (int i = tid; i < STG0 * 256; i += BLK_THREADS) ldsB[i] = BfragG[i];

    // full index chain up front: 54 coalesced loads, mask fused -> zero row
    int mi[K_VOL];
    if (active) {
#pragma unroll
        for (int k = 0; k < K_VOL; ++k) {
            const int ix = in_idx[k * M_VOX + m0 + col];
            const int mk = mask[k * M_VOX + m0 + col];
            mi[k] = mk ? ix : N_VOX;
        }
    }
    __syncthreads();   // LDS stage 0 ready

    floatx4 acc0 = {0.f,0.f,0.f,0.f}, acc1 = {0.f,0.f,0.f,0.f};
    floatx4 acc2 = {0.f,0.f,0.f,0.f}, acc3 = {0.f,0.f,0.f,0.f};
    const bf16x8* lbase = ldsB + lane;
    const __bf16* fbase = featsB + quad * 8;

    bf16x8 A[BURST];

    if (active) {
        // ---- stage 0, batch 0: offsets 0..6 ----
#pragma unroll
        for (int j = 0; j < BURST; ++j)
            A[j] = *(const bf16x8*)(fbase + (size_t)mi[j] * C_IN);
#pragma unroll
        for (int j = 0; j < BURST; ++j) {
            const int k = j;
            bf16x8 b0 = lbase[k * 256 + 0 * 64];
            bf16x8 b1 = lbase[k * 256 + 1 * 64];
            bf16x8 b2 = lbase[k * 256 + 2 * 64];
            bf16x8 b3 = lbase[k * 256 + 3 * 64];
            acc0 = __builtin_amdgcn_mfma_f32_16x16x32_bf16(A[j], b0, acc0, 0, 0, 0);
            acc1 = __builtin_amdgcn_mfma_f32_16x16x32_bf16(A[j], b1, acc1, 0, 0, 0);
            acc2 = __builtin_amdgcn_mfma_f32_16x16x32_bf16(A[j], b2, acc2, 0, 0, 0);
            acc3 = __builtin_amdgcn_mfma_f32_16x16x32_bf16(A[j], b3, acc3, 0, 0, 0);
        }
        // ---- stage 0, batch 1: offsets 7..13 ----
#pragma unroll
        for (int j = 0; j < BURST; ++j)
            A[j] = *(const bf16x8*)(fbase + (size_t)mi[BURST + j] * C_IN);
#pragma unroll
        for (int j = 0; j < BURST; ++j) {
            const int k = BURST + j;
            bf16x8 b0 = lbase[k * 256 + 0 * 64];
            bf16x8 b1 = lbase[k * 256 + 1 * 64];
            bf16x8 b2 = lbase[k * 256 + 2 * 64];
            bf16x8 b3 = lbase[k * 256 + 3 * 64];
            acc0 = __builtin_amdgcn_mfma_f32_16x16x32_bf16(A[j], b0, acc0, 0, 0, 0);
            acc1 = __builtin_amdgcn_mfma_f32_16x16x32_bf16(A[j], b1, acc1, 0, 0, 0);
            acc2 = __builtin_amdgcn_mfma_f32_16x16x32_bf16(A[j], b2, acc2, 0, 0, 0);
            acc3 = __builtin_amdgcn_mfma_f32_16x16x32_bf16(A[j], b3, acc3, 0, 0, 0);
        }
    }

    // ---- restage LDS with offsets 14..26 ----
    __syncthreads();   // everyone done reading LDS stage 0
#pragma unroll
    for (int i = tid; i < STG1 * 256; i += BLK_THREADS)
        ldsB[i] = BfragG[STG0 * 256 + i];
    __syncthreads();   // LDS stage 1 ready

    if (active) {
        // ---- stage 1, batch 0: offsets 14..20 ----
#pragma unroll
        for (int j = 0; j < BURST; ++j)
            A[j] = *(const bf16x8*)(fbase + (size_t)mi[STG0 + j] * C_IN);
#pragma unroll
        for (int j = 0; j < BURST; ++j) {
            const int k = j;
            bf16x8 b0 = lbase[k * 256 + 0 * 64];
            bf16x8 b1 = lbase[k * 256 + 1 * 64];
            bf16x8 b2 = lbase[k * 256 + 2 * 64];
            bf16x8 b3 = lbase[k * 256 + 3 * 64];
            acc0 = __builtin_amdgcn_mfma_f32_16x16x32_bf16(A[j], b0, acc0, 0, 0, 0);
            acc1 = __builtin_amdgcn_mfma_f32_16x16x32_bf16(A[j], b1, acc1, 0, 0, 0);
            acc2 = __builtin_amdgcn_mfma_f32_16x16x32_bf16(A[j], b2, acc2, 0, 0, 0);
            acc3 = __builtin_amdgcn_mfma_f32_16x16x32_bf16(A[j], b3, acc3, 0, 0, 0);
        }
        // ---- stage 1, batch 1: offsets 21..26 (6 iters) ----
#pragma unroll
        for (int j = 0; j < STG1 - BURST; ++j)
            A[j] = *(const bf16x8*)(fbase + (size_t)mi[STG0 + BURST + j] * C_IN);
#pragma unroll
        for (int j = 0; j < STG1 - BURST; ++j) {
            const int k = BURST + j;
            bf16x8 b0 = lbase[k * 256 + 0 * 64];
            bf16x8 b1 = lbase[k * 256 + 1 * 64];
            bf16x8 b2 = lbase[k * 256 + 2 * 64];
            bf16x8 b3 = lbase[k * 256 + 3 * 64];
            acc0 = __builtin_amdgcn_mfma_f32_16x16x32_bf16(A[j], b0, acc0, 0, 0, 0);
            acc1 = __builtin_amdgcn_mfma_f32_16x16x32_bf16(A[j], b1, acc1, 0, 0, 0);
            acc2 = __builtin_amdgcn_mfma_f32_16x16x32_bf16(A[j], b2, acc2, 0, 0, 0);
            acc3 = __builtin_amdgcn_mfma_f32_16x16x32_bf16(A[j], b3, acc3, 0, 0, 0);
        }

        float* op = out + (size_t)(m0 + quad * 4) * C_OUT + col;
#pragma unroll
        for (int r = 0; r < 4; ++r) {
            op[r * C_OUT + 0]  = acc0[r];
            op[r * C_OUT + 16] = acc1[r];
            op[r * C_OUT + 32] = acc2[r];
            op[r * C_OUT + 48] = acc3[r];
        }
    }
}

extern "C" void kernel_launch(void* const* d_in, const int* in_sizes, int n_in,
                              void* d_out, int out_size, void* d_ws, size_t ws_size,
                              hipStream_t stream) {
    const float* feats   = (const float*)d_in[0];
    const float* kernelw = (const float*)d_in[1];
    const int*   in_idx  = (const int*)d_in[2];
    const int*   maskp   = (const int*)d_in[3];
    float*       out     = (float*)d_out;

    __bf16* featsB = (__bf16*)d_ws;
    bf16x8* BfragP = (bf16x8*)((char*)d_ws + BFRAG_OFF);

    prep_all<<<dim3(FEAT_BLOCKS + K_VOL), dim3(256), 0, stream>>>(
        feats, kernelw, featsB, BfragP);

    const int blocks = (M_VOX + VOX_PER_BLK - 1) / VOX_PER_BLK;   // 782
    sparse_conv_mfma<<<dim3(blocks), dim3(BLK_THREADS), 0, stream>>>(
        featsB, BfragP, in_idx, maskp, out);
}